// Round 4
// baseline (471.266 us; speedup 1.0000x reference)
//
#include <hip/hip_runtime.h>
#include <hip/hip_bf16.h>
#include <math.h>

// ============================================================================
// MinimalNetwork, round 18: code-footprint shrink (I-cache theory).
// r17 post-mortem: occupancy 19->29% yet fused 204->220us; VALU 18%, MFMA 6%,
// HBM 4%, conflicts 2% -> all pipes idle, more waves slightly WORSE. Only
// surviving candidate: I-fetch thrash (19 unrolled template phases ~50-60KB
// straight-line code vs 32KB I$; 12 waves at different PCs refetch from L2).
// Change (single variable vs r17):
//   - 19 phase<LO,LI,LF> bodies -> 9 phase_group<LO,LI> bodies looping over
//     lf at RUNTIME (#pragma unroll 1; nf=2lf+1; C3 base = CB_OFF[chunk] via
//     __device__ table). kv section rolled (runtime nf) reading C3g/rshrow
//     straight from global (L1-resident, consumed after the wave_barrier).
//   - MFMA + consume sections byte-identical structure to r17 (compile-time
//     NO/NI; no dynamic-indexed register arrays).
// Kill criterion: dur >=200us & VALU ~18% -> I$ theory dead, ablate sections.
// ============================================================================

#define FEATD 72
#define NCOL 1216
#define SWISH_SCALE 1.679177f

typedef __attribute__((ext_vector_type(8))) short bf16x8;
typedef __attribute__((ext_vector_type(4))) float f32x4;

// ---- 19 (lo,li,lf) chunks; CB_OFF = offsets into the C3 coefficient pool ----
constexpr int NCOMBO = 19;
constexpr int CB_LO[NCOMBO] = {0,0,0,1,1,1,1,1,1,1,2,2,2,2,2,2,2,2,2};
constexpr int CB_LI[NCOMBO] = {0,1,2,0,1,1,1,2,2,2,0,1,1,1,2,2,2,2,2};
constexpr int CB_LF[NCOMBO] = {0,1,2,1,0,1,2,1,2,3,2,1,2,3,0,1,2,3,4};
constexpr int CB_OFF[NCOMBO] = {0,1,10,35,44,53,80,125,170,245,350,375,420,495,600,625,700,825,1000};
constexpr int CB_SZ[NCOMBO]  = {1,9,25,9,9,27,45,45,75,105,25,45,75,105,25,75,125,175,225};
constexpr int C3TOT = 1225;

__device__ const int d_cboff[NCOMBO] = {0,1,10,35,44,53,80,125,170,245,350,375,420,495,600,625,700,825,1000};

constexpr int ROFFT[3][3] = {{0,64,128},{192,256,448},{640,704,896}};
constexpr int FOFFT[3]   = {0,8,32};

__device__ const double d_fact[11] = {1.,1.,2.,6.,24.,120.,720.,5040.,40320.,362880.,3628800.};

// ---------------------------------------------------------------------------
// Wigner 3j (complex basis, Racah) in double precision + real change of basis
// ---------------------------------------------------------------------------
__device__ double w3j_entry(int j1,int j2,int j3,int m1,int m2,int m3){
  if (m1+m2+m3 != 0) return 0.0;
  int dj = j1-j2; if (dj<0) dj=-dj;
  if (j3 < dj || j3 > j1+j2) return 0.0;
  int t1 = j2 - m1 - j3, t2 = j1 + m2 - j3;
  int kmin = 0; if (t1>kmin) kmin=t1; if (t2>kmin) kmin=t2;
  int kmax = j1+j2-j3; if (j1-m1<kmax) kmax=j1-m1; if (j2+m2<kmax) kmax=j2+m2;
  double s = 0.0;
  for (int k=kmin;k<=kmax;++k){
    double den = d_fact[k]*d_fact[k-t1]*d_fact[k-t2]*d_fact[j1+j2-j3-k]
               * d_fact[j1-m1-k]*d_fact[j2+m2-k];
    s += ((k&1)? -1.0:1.0)/den;
  }
  double pref = sqrt(d_fact[j1+j2-j3]*d_fact[j1-j2+j3]*d_fact[-j1+j2+j3]/d_fact[j1+j2+j3+1]
               * d_fact[j1+m1]*d_fact[j1-m1]*d_fact[j2+m2]*d_fact[j2-m2]
               * d_fact[j3+m3]*d_fact[j3-m3]);
  int ex = j1-j2-m3;
  if (ex & 1) pref = -pref;
  return pref*s;
}

__device__ void cob(int l, int r, int c, double& re, double& im){
  re = 0.0; im = 0.0;
  int mr = r - l, mc = c - l;
  const double s = 0.70710678118654752440;
  if (mr == 0) { if (mc == 0) re = 1.0; return; }
  if (mr > 0) {
    if (mc == mr)       re = (mr & 1) ? -s : s;
    else if (mc == -mr) re = s;
  } else {
    int m = -mr;
    if (mc == -m)      im = s;
    else if (mc == m)  im = (m & 1) ? s : -s;
  }
}

__global__ void c3_build_kernel(double* __restrict__ Tre, double* __restrict__ Tim){
  int idx = blockIdx.x*64 + threadIdx.x;
  if (idx >= C3TOT) return;
  int c = 0;
  while (c+1 < NCOMBO && idx >= CB_OFF[c+1]) ++c;
  int lo = CB_LO[c], li = CB_LI[c], lf = CB_LF[c];
  int n2 = 2*li+1, n3 = 2*lf+1;
  int loc = idx - CB_OFF[c];
  int a = loc/(n2*n3), b = (loc/n3)%n2, g = loc%n3;
  double sre=0.0, sim=0.0;
  for (int m1=-lo; m1<=lo; ++m1){
    for (int m2=-li; m2<=li; ++m2){
      int m3 = -m1-m2;
      if (m3 < -lf || m3 > lf) continue;
      double w = w3j_entry(lo,li,lf,m1,m2,m3);
      if (w == 0.0) continue;
      double r1,i1,r2,i2,r3,i3;
      cob(lo, a, m1+lo, r1,i1);
      cob(li, b, m2+li, r2,i2);
      cob(lf, g, m3+lf, r3,i3);
      double rr = r1*r2 - i1*i2, ri = r1*i2 + i1*r2;
      double fr = rr*r3 - ri*i3, fi = rr*i3 + ri*r3;
      sre += fr*w; sim += fi*w;
    }
  }
  Tre[idx] = sre; Tim[idx] = sim;
}

__global__ void c3_norm_kernel(const double* __restrict__ Tre, const double* __restrict__ Tim,
                               float* __restrict__ C3f){
  int c = blockIdx.x;
  int off = CB_OFF[c], sz = CB_SZ[c];
  int t = threadIdx.x;
  double sre=0.0, sim=0.0;
  for (int p=t; p<sz; p+=64){ double x=Tre[off+p], y=Tim[off+p]; sre+=x*x; sim+=y*y; }
  for (int m=1; m<64; m<<=1){ sre += __shfl_xor(sre, m, 64); sim += __shfl_xor(sim, m, 64); }
  bool useRe = (sre >= sim);
  double n = sqrt(useRe ? sre : sim);
  double inv = (n > 0.0) ? 1.0/n : 1.0;
  for (int p=t; p<sz; p+=64){
    double v = useRe ? Tre[off+p] : Tim[off+p];
    C3f[off+p] = (float)(v*inv);
  }
}

// ---------------------------------------------------------------------------
// W3t[c'][k] chunk-major. 0.1 scale folded. Pitch 136, pad zeroed.
// ---------------------------------------------------------------------------
__global__ __launch_bounds__(256) void prep_w3t_kernel(const float* __restrict__ W3,
                                                       __hip_bfloat16* __restrict__ W3t){
  int idx = blockIdx.x*256 + threadIdx.x;
  if (idx >= 1216*136) return;
  int cp = idx/136, k = idx%136;
  int chunk = cp>>6, uv = cp&63;
  int lo = CB_LO[chunk], li = CB_LI[chunk], lf = CB_LF[chunk];
  int lmin = lo<li ? lo : li;
  int nlf = 2*lmin+1;
  int fi = lf - (lo>li ? lo-li : li-lo);
  int c = ROFFT[lo][li] + uv*nlf + fi;
  float v = (k < 100) ? 0.1f*W3[(size_t)k*NCOL + c] : 0.f;
  W3t[idx] = __float2bfloat16(v);
}

// Wt[o][k] = bf16(0.1*W[k][o]), o<112 (rows 100..111 zero), k<136 (k>=100 zero)
// Both W1 and W2 in one launch.
__global__ __launch_bounds__(256) void prep_wt_kernel(const float* __restrict__ W1,
                                                      const float* __restrict__ W2,
                                                      __hip_bfloat16* __restrict__ W1t,
                                                      __hip_bfloat16* __restrict__ W2t){
  int idx = blockIdx.x*256 + threadIdx.x;
  constexpr int HALF = 112*136;
  if (idx >= 2*HALF) return;
  const float* W = (idx < HALF) ? W1 : W2;
  __hip_bfloat16* Wt = (idx < HALF) ? W1t : W2t;
  int r = (idx < HALF) ? idx : idx - HALF;
  int o = r/136, k = r%136;
  float v = (o < 100 && k < 100) ? 0.1f*W[k*100+o] : 0.f;
  Wt[r] = __float2bfloat16(v);
}

// ---------------------------------------------------------------------------
// Radial MLP with MFMA layers 2,3. 64 edges/block, 4 waves, 4 blocks/CU.
// ---------------------------------------------------------------------------
__device__ __forceinline__ float swishf(float s){
  return SWISH_SCALE * s / (1.f + __expf(-s));
}

__device__ __forceinline__ void radial_layer_mfma(
    const __hip_bfloat16* __restrict__ sIn,   // [64][136] bf16, rows e
    const __hip_bfloat16* __restrict__ Wt,    // [112][136] bf16 global
    __hip_bfloat16* __restrict__ sOut,        // [64][136] bf16
    int wv, int lr, int lq)
{
  bf16x8 bf[4];
  #pragma unroll
  for (int ks=0; ks<4; ++ks)
    bf[ks] = *(const bf16x8*)&sIn[(wv*16+lr)*136 + ks*32 + lq*8];
  f32x4 acc[7] = {};
  #pragma unroll
  for (int ks=0; ks<4; ++ks)
    #pragma unroll
    for (int ot=0; ot<7; ++ot){
      bf16x8 a = *(const bf16x8*)&Wt[(ot*16+lr)*136 + ks*32 + lq*8];
      acc[ot] = __builtin_amdgcn_mfma_f32_16x16x32_bf16(a, bf[ks], acc[ot], 0, 0, 0);
    }
  // C frag: col(lr)=e within wave, row(ot*16+lq*4+r)=o.  swish + bf16 + short4.
  #pragma unroll
  for (int ot=0; ot<7; ++ot){
    __hip_bfloat16 hv[4];
    #pragma unroll
    for (int r=0; r<4; ++r)
      hv[r] = __float2bfloat16(swishf(acc[ot][r]));   // Wt rows o>=100 zero -> swish(0)=0
    *(short4*)&sOut[(wv*16+lr)*136 + ot*16 + lq*4] = *(short4*)hv;
  }
  // zero o/k = 112..127 of own rows COMPLETELY: 64 lanes = 16 rows x 4 quarters
  {
    int lane = lq*16 + lr;            // 0..63
    int row = lane & 15, q = lane >> 4;   // q in 0..3
    short4 z = {0,0,0,0};
    *(short4*)&sOut[(wv*16+row)*136 + 112 + q*4] = z;
  }
}

__global__ __launch_bounds__(256,4) void radial_mfma_kernel(
    const float* __restrict__ radii, const float* __restrict__ W0,
    const __hip_bfloat16* __restrict__ W1t, const __hip_bfloat16* __restrict__ W2t,
    __hip_bfloat16* __restrict__ h_bf, int E)
{
  __shared__ float sbas[640];
  __shared__ __align__(16) __hip_bfloat16 sA[64*136];  // h1, then h3
  __shared__ __align__(16) __hip_bfloat16 sB[64*136];  // h2
  const int t = threadIdx.x;
  const int et0 = blockIdx.x*64;

  for (int p=t; p<640; p+=256){
    int er = p/10, k = p%10;
    int eg = et0 + er;
    float r = (eg < E) ? radii[eg] : 0.f;
    float c = 0.7f + (2.5f/9.0f)*(float)k;
    float d = (r - c) * (9.0f/2.5f);
    sbas[p] = __expf(-d*d);
  }
  __syncthreads();
  // layer 1 (K=10, VALU), h1 bf16 into sA; zero k-pad 100..135
  for (int p=t; p<6400; p+=256){
    int er = p/100, o = p%100;
    float s = 0.f;
    #pragma unroll
    for (int k=0;k<10;++k) s += sbas[er*10+k]*W0[k*100+o];
    sA[er*136+o] = __float2bfloat16(swishf(s*0.3162277660168379f));   // 1/sqrt(10)
  }
  for (int p=t; p<64*36; p+=256){
    int er = p/36, k = 100 + p%36;
    sA[er*136+k] = __float2bfloat16(0.f);
  }
  __syncthreads();   // everything below is wave-local (own 16 edge rows)

  const int lane = t & 63, wv = t >> 6;
  const int lr = lane & 15, lq = lane >> 4;

  radial_layer_mfma(sA, W1t, sB, wv, lr, lq);   // h2 = swish(0.1*h1@W1)
  __builtin_amdgcn_wave_barrier();
  radial_layer_mfma(sB, W2t, sA, wv, lr, lq);   // h3 = swish(0.1*h2@W2)
  __builtin_amdgcn_wave_barrier();
  // copy own 16 rows (16*136 bf16 = 272 float4) to global
  {
    const float4* sm = (const float4*)(sA + (size_t)(wv*16)*136);
    float4* gm = (float4*)(h_bf + (size_t)(et0 + wv*16)*136);
    for (int p=lane; p<272; p+=64) gm[p] = sm[p];
  }
}

// ---------------------------------------------------------------------------
// CSR of edges by target node
// ---------------------------------------------------------------------------
__global__ __launch_bounds__(256) void hist_kernel(const int* __restrict__ ei,
                                                   int* __restrict__ deg, int E){
  int e = blockIdx.x*256 + threadIdx.x;
  if (e < E) atomicAdd(&deg[ei[E+e]], 1);
}

__global__ __launch_bounds__(256) void scan_kernel(const int* __restrict__ deg,
                                                   int* __restrict__ off,
                                                   int* __restrict__ cursor, int N, int E){
  __shared__ int part[256], spref[256];
  const int t = threadIdx.x;
  const int CH = (N + 255)/256;
  int lo = t*CH, hi = lo+CH < N ? lo+CH : N;
  int s = 0;
  for (int n=lo; n<hi; ++n) s += deg[n];
  part[t] = s;
  __syncthreads();
  if (t == 0){
    int run = 0;
    for (int i=0;i<256;++i){ spref[i] = run; run += part[i]; }
  }
  __syncthreads();
  int run = spref[t];
  for (int n=lo; n<hi; ++n){ off[n] = run; cursor[n] = run; run += deg[n]; }
  if (t == 255) off[N] = E;
}

__global__ __launch_bounds__(256) void fill_kernel(const int* __restrict__ ei,
                                                   int* __restrict__ cursor,
                                                   int* __restrict__ eid, int E){
  int e = blockIdx.x*256 + threadIdx.x;
  if (e < E){
    int idx = atomicAdd(&cursor[ei[E+e]], 1);
    eid[idx] = e;
  }
}

// ---------------------------------------------------------------------------
// Gather: one 64-lane wave per node; writes every output element exactly once.
// ---------------------------------------------------------------------------
__global__ __launch_bounds__(64) void gather_kernel(const float* __restrict__ msg,
                                                    const int* __restrict__ off,
                                                    const int* __restrict__ eid,
                                                    float* __restrict__ out, int N){
  const int n = blockIdx.x;
  const int t = threadIdx.x;
  const int s = off[n], e1 = off[n+1];
  float a0 = 0.f, a1 = 0.f;
  for (int i=s; i<e1; ++i){
    const float* m = msg + (size_t)eid[i]*FEATD;
    a0 += m[t];
    if (t < 8) a1 += m[64+t];
  }
  out[(size_t)n*FEATD + t] = a0;
  if (t < 8) out[(size_t)n*FEATD + 64 + t] = a1;
}

// ---------------------------------------------------------------------------
// Fused GEMM+TP: 9 phase_group bodies (runtime lf loop) instead of 19 inlined
// phases -> ~2x smaller hot code. LDS 52736 B, 3 blocks/CU.
// ---------------------------------------------------------------------------
constexpr int OF_RT  = 0;         // 64*68 f32 = 17408  ([e][68] row layout)
constexpr int OF_ACC = 17408;     // 64*40 f32 = 10240  (live LO-group slice)
constexpr int OF_F   = 27648;     // 64*72 f32 = 18432
constexpr int OF_KV  = 46080;     // 64*25 f32 = 6400
constexpr int OF_SRC = 52480;     // 64 int = 256
constexpr int SMEM_SZ = 52736;    // 51.5 KB -> 3 blocks/CU

template<int LO,int LI>
__device__ __forceinline__ void phase_group(
    int chunk0, int lf0, int nlf,
    const __hip_bfloat16* __restrict__ W3t, const bf16x8 (&hf)[4],
    float* sRt, float* sFf, float* sKV,
    const float* __restrict__ C3g, const float* __restrict__ rshrow,
    float* sAcc, int t)
{
  constexpr int NO = 2*LO+1, NI = 2*LI+1;
  constexpr int FO = FOFFT[LI];

  const int e = t >> 2, role = t & 3;
  const int lane = t & 63, wv = t >> 6;
  const int lr = lane & 15, lq = lane >> 4;

  #pragma unroll 1
  for (int i = 0; i < nlf; ++i){
    const int chunk = chunk0 + i;
    const int lf    = lf0 + i;
    const int nf    = 2*lf + 1;
    const int c3b   = d_cboff[chunk];
    const int yb    = lf*lf;

    // ---- 1. kv[e][o*NI+mi] = sum_mf C3 * y : quad-split (wave-local) ----
    // C3 + rsh from global (L1-resident), rolled runtime-nf loop; result
    // consumed only after the wave_barrier -> latency hidden under MFMA.
    #pragma unroll 1
    for (int it = role; it < NO*NI; it += 4){
      float s = 0.f;
      for (int mf = 0; mf < nf; ++mf)
        s += C3g[c3b + it*nf + mf] * rshrow[yb + mf];
      sKV[e*25 + it] = s;
    }
    // ---- 2. MFMA: Rt[e][c], A straight from global; b128 LDS stores ----
    {
      const __hip_bfloat16* wb = W3t + (size_t)chunk*64*136;
      f32x4 a4[4] = {};
      #pragma unroll
      for (int ks=0; ks<4; ++ks){
        #pragma unroll
        for (int ct=0; ct<4; ++ct){
          bf16x8 a = *(const bf16x8*)&wb[(ct*16+lr)*136 + ks*32 + lq*8];
          a4[ct] = __builtin_amdgcn_mfma_f32_16x16x32_bf16(a, hf[ks], a4[ct], 0, 0, 0);
        }
      }
      #pragma unroll
      for (int ct=0; ct<4; ++ct)
        *(f32x4*)&sRt[(wv*16 + lr)*68 + ct*16 + lq*4] = a4[ct];
    }
    __builtin_amdgcn_wave_barrier();

    // ---- 3. consume (H-trick): H[du][mi] = sum_v R[u,v]*F[v,mi] ----
    {
      float H[2][NI];
      #pragma unroll
      for (int du=0; du<2; ++du)
        #pragma unroll
        for (int mi=0; mi<NI; ++mi) H[du][mi] = 0.f;

      #pragma unroll
      for (int vg=0; vg<2; ++vg){
        float fb[4*NI];
        #pragma unroll
        for (int p=0; p<NI; ++p)
          *(f32x4*)&fb[p*4] = *(const f32x4*)&sFf[e*72 + FO + vg*4*NI + p*4];
        #pragma unroll
        for (int du=0; du<2; ++du){
          const int u = role*2 + du;
          f32x4 rv = *(const f32x4*)&sRt[e*68 + u*8 + vg*4];
          #pragma unroll
          for (int v=0; v<4; ++v)
            #pragma unroll
            for (int mi=0; mi<NI; ++mi)
              H[du][mi] += rv[v] * fb[v*NI + mi];
        }
      }
      // accumulate into group-local LDS slice (pitch 40):
      // LO=0: col=u (0..7); LO=1: col=u*3+o (0..23); LO=2: col=u*5+o (0..39)
      const int u0 = role*2, u1 = role*2 + 1;
      const int b0 = e*40 + ((LO==0) ? u0 : (LO==1) ? u0*3 : u0*5);
      const int b1 = e*40 + ((LO==0) ? u1 : (LO==1) ? u1*3 : u1*5);
      #pragma unroll
      for (int o=0; o<NO; ++o){
        float s0 = 0.f, s1 = 0.f;
        #pragma unroll
        for (int mi=0; mi<NI; ++mi){
          float kvv = sKV[e*25 + o*NI + mi];
          s0 += kvv * H[0][mi];
          s1 += kvv * H[1][mi];
        }
        sAcc[b0 + o] += s0;
        sAcc[b1 + o] += s1;
      }
    }
    __builtin_amdgcn_wave_barrier();
  }
}

// Wave-local flush of the LO-group accumulator slice: sAcc rows 16wv..16wv+15
// are written only by wave wv, so no block-wide sync is needed.
template<int J0,int W>
__device__ __forceinline__ void flush_group(float* sAcc, float* __restrict__ msg,
                                            int eb, int t, float nrm)
{
  const int lane = t & 63, wv = t >> 6;
  __builtin_amdgcn_wave_barrier();
  for (int p = lane; p < 16*W; p += 64){
    int el = wv*16 + p/W, j = p%W;
    msg[(size_t)(eb + el)*FEATD + J0 + j] = nrm * sAcc[el*40 + j];
    sAcc[el*40 + j] = 0.f;                 // ready for next group
  }
  __builtin_amdgcn_wave_barrier();
}

__global__ __launch_bounds__(256,3) void fused_kernel(
    const float* __restrict__ feats, const int* __restrict__ ei,
    const float* __restrict__ rsh, const __hip_bfloat16* __restrict__ h_bf,
    const __hip_bfloat16* __restrict__ W3t, const float* __restrict__ C3g,
    float* __restrict__ msg, int E)
{
  __shared__ __align__(16) char smem[SMEM_SZ];
  float* sRt  = (float*)(smem + OF_RT);
  float* sAcc = (float*)(smem + OF_ACC);
  float* sFf  = (float*)(smem + OF_F);
  float* sKV  = (float*)(smem + OF_KV);
  int*   sSrc = (int*)(smem + OF_SRC);

  const int t = threadIdx.x;
  const int eb = blockIdx.x*64;

  bf16x8 hf[4];
  {
    const int lane = t & 63, wv = t >> 6;
    const int lr = lane & 15, lq = lane >> 4;
    const __hip_bfloat16* hrow = h_bf + (size_t)(eb + wv*16 + lr)*136;
    #pragma unroll
    for (int ks=0; ks<4; ++ks)
      hf[ks] = *(const bf16x8*)&hrow[ks*32 + lq*8];
  }
  for (int p=t; p<2560; p+=256) sAcc[p] = 0.f;
  for (int p=t; p<64; p+=256){
    int e = eb + p;
    sSrc[p] = (e < E) ? ei[e] : 0;
  }
  __syncthreads();
  for (int p=t; p<64*72; p+=256){
    int el = p/72, j = p%72;
    sFf[el*72 + j] = feats[(size_t)sSrc[el]*72 + j];
  }
  __syncthreads();

  // own-edge rsh row, pad-clamped (pad rows' msg is never read by gather)
  int eg = eb + (t >> 2); if (eg > E-1) eg = E-1;
  const float* rshrow = rsh + (size_t)eg*25;

  // ---- group LO=0: output cols 0..7 ----
  phase_group<0,0>( 0, 0, 1, W3t, hf, sRt, sFf, sKV, C3g, rshrow, sAcc, t);
  phase_group<0,1>( 1, 1, 1, W3t, hf, sRt, sFf, sKV, C3g, rshrow, sAcc, t);
  phase_group<0,2>( 2, 2, 1, W3t, hf, sRt, sFf, sKV, C3g, rshrow, sAcc, t);
  flush_group<0,8>(sAcc, msg, eb, t, 0.72360125f);

  // ---- group LO=1: output cols 8..31 ----
  phase_group<1,0>( 3, 1, 1, W3t, hf, sRt, sFf, sKV, C3g, rshrow, sAcc, t);
  phase_group<1,1>( 4, 0, 3, W3t, hf, sRt, sFf, sKV, C3g, rshrow, sAcc, t);
  phase_group<1,2>( 7, 1, 3, W3t, hf, sRt, sFf, sKV, C3g, rshrow, sAcc, t);
  flush_group<8,24>(sAcc, msg, eb, t, 0.8204867f);

  // ---- group LO=2: output cols 32..71 ----
  phase_group<2,0>(10, 2, 1, W3t, hf, sRt, sFf, sKV, C3g, rshrow, sAcc, t);
  phase_group<2,1>(11, 1, 3, W3t, hf, sRt, sFf, sKV, C3g, rshrow, sAcc, t);
  phase_group<2,2>(14, 0, 5, W3t, hf, sRt, sFf, sKV, C3g, rshrow, sAcc, t);
  flush_group<32,40>(sAcc, msg, eb, t, 0.9341652f);
}

// ---------------------------------------------------------------------------
extern "C" void kernel_launch(void* const* d_in, const int* in_sizes, int n_in,
                              void* d_out, int out_size, void* d_ws, size_t ws_size,
                              hipStream_t stream)
{
  const float* feats = (const float*)d_in[0];
  const int*   ei    = (const int*)d_in[1];
  const float* radii = (const float*)d_in[2];
  const float* rsh   = (const float*)d_in[3];
  const float* W0    = (const float*)d_in[4];
  const float* W1    = (const float*)d_in[5];
  const float* W2    = (const float*)d_in[6];
  const float* W3    = (const float*)d_in[7];
  float* out = (float*)d_out;
  const int E = in_sizes[2];
  const int N = in_sizes[0]/FEATD;

  const int EPAD = ((E + 63)/64)*64;
  const int NBLK = EPAD/64;

  char* ws = (char*)d_ws;
  size_t off_b = 0;
  float*  C3f = (float*)(ws + off_b);  off_b += 8192;
  double* Tre = (double*)(ws + off_b); off_b += 12288;
  double* Tim = (double*)(ws + off_b); off_b += 12288;          // 32768
  __hip_bfloat16* W3t = (__hip_bfloat16*)(ws + off_b); off_b += 335872;
  __hip_bfloat16* W1t = (__hip_bfloat16*)(ws + off_b); off_b += 30720;   // 112*136 bf16
  __hip_bfloat16* W2t = (__hip_bfloat16*)(ws + off_b); off_b += 30720;
  __hip_bfloat16* h_bf = (__hip_bfloat16*)(ws + off_b); off_b += (size_t)EPAD*272;
  float* msg = (float*)(ws + off_b);   off_b += (size_t)EPAD*FEATD*4;
  int* deg    = (int*)(ws + off_b);    off_b += (size_t)N*4;
  int* offv   = (int*)(ws + off_b);    off_b += (size_t)(N+1)*4;
  int* cursor = (int*)(ws + off_b);    off_b += (size_t)N*4;
  int* eid    = (int*)(ws + off_b);    off_b += (size_t)E*4;

  // constants / tables
  c3_build_kernel<<<dim3((C3TOT+63)/64), dim3(64), 0, stream>>>(Tre, Tim);
  c3_norm_kernel<<<dim3(NCOMBO), dim3(64), 0, stream>>>(Tre, Tim, C3f);
  prep_w3t_kernel<<<dim3((1216*136+255)/256), dim3(256), 0, stream>>>(W3, W3t);
  prep_wt_kernel<<<dim3((2*112*136+255)/256), dim3(256), 0, stream>>>(W1, W2, W1t, W2t);

  // CSR of edges by target
  hipMemsetAsync(deg, 0, (size_t)N*4, stream);
  hist_kernel<<<dim3((E+255)/256), dim3(256), 0, stream>>>(ei, deg, E);
  scan_kernel<<<dim3(1), dim3(256), 0, stream>>>(deg, offv, cursor, N, E);
  fill_kernel<<<dim3((E+255)/256), dim3(256), 0, stream>>>(ei, cursor, eid, E);

  // main pipeline
  radial_mfma_kernel<<<dim3(NBLK), dim3(256), 0, stream>>>(radii, W0, W1t, W2t, h_bf, E);
  fused_kernel<<<dim3(NBLK), dim3(256), 0, stream>>>(feats, ei, rsh, h_bf, W3t, C3f, msg, E);
  gather_kernel<<<dim3(N), dim3(64), 0, stream>>>(msg, offv, eid, out, N);
}

// Round 5
// 373.157 us; speedup vs baseline: 1.2629x; 1.2629x over previous
//
#include <hip/hip_runtime.h>
#include <hip/hip_bf16.h>
#include <math.h>

// ============================================================================
// MinimalNetwork, round 19: stage W3t chunks into LDS (coalesced) instead of
// 16 per-lane strided global b128 loads per phase.
// r18 post-mortem: I$ theory refuted (smaller code = slower, VALU still 18%).
// Remaining candidate: MFMA A-operand fetch — per-lane loads at 272B row
// stride touch 16 cache lines per instruction, 256 line-requests/wave/phase,
// re-gathered by every wave from L1/L2 (invisible in FETCH: L2-resident).
// Fix (Guideline 3 + rule #21):
//   - W3t repacked to pitch-128 (16KB/chunk, MFMA reads k<128 only) and
//     PRE-SWIZZLED in prep: unit16 = (row*16 + (k>>3)) ^ (row&7).
//   - per phase: sync -> 4x global_load_lds(16B)/wave (linear LDS dest)
//     -> kv section (overlaps stage latency) -> sync (drains vmcnt)
//     -> MFMA A via swizzled ds_read_b128 (2-way bank alias = free).
//   - kv back to LDS C3+rsh (r14 form). LDS 80432 B -> 2 blocks/CU.
// Kill criterion: fused >=180us & pipes <25% -> probe ablation next round.
// ============================================================================

#define FEATD 72
#define NCOL 1216
#define SWISH_SCALE 1.679177f

typedef __attribute__((ext_vector_type(8))) short bf16x8;
typedef __attribute__((ext_vector_type(4))) float f32x4;

// ---- 19 (lo,li,lf) chunks; CB_OFF = offsets into the C3 coefficient pool ----
constexpr int NCOMBO = 19;
constexpr int CB_LO[NCOMBO] = {0,0,0,1,1,1,1,1,1,1,2,2,2,2,2,2,2,2,2};
constexpr int CB_LI[NCOMBO] = {0,1,2,0,1,1,1,2,2,2,0,1,1,1,2,2,2,2,2};
constexpr int CB_LF[NCOMBO] = {0,1,2,1,0,1,2,1,2,3,2,1,2,3,0,1,2,3,4};
constexpr int CB_OFF[NCOMBO] = {0,1,10,35,44,53,80,125,170,245,350,375,420,495,600,625,700,825,1000};
constexpr int CB_SZ[NCOMBO]  = {1,9,25,9,9,27,45,45,75,105,25,45,75,105,25,75,125,175,225};
constexpr int C3TOT = 1225;

constexpr int C3OFFT[3][3][5] = {
  { {0,-1,-1,-1,-1}, {-1,1,-1,-1,-1}, {-1,-1,10,-1,-1} },
  { {-1,35,-1,-1,-1}, {44,53,80,-1,-1}, {-1,125,170,245,-1} },
  { {-1,-1,350,-1,-1}, {-1,375,420,495,-1}, {600,625,700,825,1000} }
};
constexpr int ROFFT[3][3] = {{0,64,128},{192,256,448},{640,704,896}};
constexpr int FOFFT[3]   = {0,8,32};

__device__ const double d_fact[11] = {1.,1.,2.,6.,24.,120.,720.,5040.,40320.,362880.,3628800.};

// ---------------------------------------------------------------------------
// Wigner 3j (complex basis, Racah) in double precision + real change of basis
// ---------------------------------------------------------------------------
__device__ double w3j_entry(int j1,int j2,int j3,int m1,int m2,int m3){
  if (m1+m2+m3 != 0) return 0.0;
  int dj = j1-j2; if (dj<0) dj=-dj;
  if (j3 < dj || j3 > j1+j2) return 0.0;
  int t1 = j2 - m1 - j3, t2 = j1 + m2 - j3;
  int kmin = 0; if (t1>kmin) kmin=t1; if (t2>kmin) kmin=t2;
  int kmax = j1+j2-j3; if (j1-m1<kmax) kmax=j1-m1; if (j2+m2<kmax) kmax=j2+m2;
  double s = 0.0;
  for (int k=kmin;k<=kmax;++k){
    double den = d_fact[k]*d_fact[k-t1]*d_fact[k-t2]*d_fact[j1+j2-j3-k]
               * d_fact[j1-m1-k]*d_fact[j2+m2-k];
    s += ((k&1)? -1.0:1.0)/den;
  }
  double pref = sqrt(d_fact[j1+j2-j3]*d_fact[j1-j2+j3]*d_fact[-j1+j2+j3]/d_fact[j1+j2+j3+1]
               * d_fact[j1+m1]*d_fact[j1-m1]*d_fact[j2+m2]*d_fact[j2-m2]
               * d_fact[j3+m3]*d_fact[j3-m3]);
  int ex = j1-j2-m3;
  if (ex & 1) pref = -pref;
  return pref*s;
}

__device__ void cob(int l, int r, int c, double& re, double& im){
  re = 0.0; im = 0.0;
  int mr = r - l, mc = c - l;
  const double s = 0.70710678118654752440;
  if (mr == 0) { if (mc == 0) re = 1.0; return; }
  if (mr > 0) {
    if (mc == mr)       re = (mr & 1) ? -s : s;
    else if (mc == -mr) re = s;
  } else {
    int m = -mr;
    if (mc == -m)      im = s;
    else if (mc == m)  im = (m & 1) ? s : -s;
  }
}

__global__ void c3_build_kernel(double* __restrict__ Tre, double* __restrict__ Tim){
  int idx = blockIdx.x*64 + threadIdx.x;
  if (idx >= C3TOT) return;
  int c = 0;
  while (c+1 < NCOMBO && idx >= CB_OFF[c+1]) ++c;
  int lo = CB_LO[c], li = CB_LI[c], lf = CB_LF[c];
  int n2 = 2*li+1, n3 = 2*lf+1;
  int loc = idx - CB_OFF[c];
  int a = loc/(n2*n3), b = (loc/n3)%n2, g = loc%n3;
  double sre=0.0, sim=0.0;
  for (int m1=-lo; m1<=lo; ++m1){
    for (int m2=-li; m2<=li; ++m2){
      int m3 = -m1-m2;
      if (m3 < -lf || m3 > lf) continue;
      double w = w3j_entry(lo,li,lf,m1,m2,m3);
      if (w == 0.0) continue;
      double r1,i1,r2,i2,r3,i3;
      cob(lo, a, m1+lo, r1,i1);
      cob(li, b, m2+li, r2,i2);
      cob(lf, g, m3+lf, r3,i3);
      double rr = r1*r2 - i1*i2, ri = r1*i2 + i1*r2;
      double fr = rr*r3 - ri*i3, fi = rr*i3 + ri*r3;
      sre += fr*w; sim += fi*w;
    }
  }
  Tre[idx] = sre; Tim[idx] = sim;
}

__global__ void c3_norm_kernel(const double* __restrict__ Tre, const double* __restrict__ Tim,
                               float* __restrict__ C3f){
  int c = blockIdx.x;
  int off = CB_OFF[c], sz = CB_SZ[c];
  int t = threadIdx.x;
  double sre=0.0, sim=0.0;
  for (int p=t; p<sz; p+=64){ double x=Tre[off+p], y=Tim[off+p]; sre+=x*x; sim+=y*y; }
  for (int m=1; m<64; m<<=1){ sre += __shfl_xor(sre, m, 64); sim += __shfl_xor(sim, m, 64); }
  bool useRe = (sre >= sim);
  double n = sqrt(useRe ? sre : sim);
  double inv = (n > 0.0) ? 1.0/n : 1.0;
  for (int p=t; p<sz; p+=64){
    double v = useRe ? Tre[off+p] : Tim[off+p];
    C3f[off+p] = (float)(v*inv);
  }
}

// ---------------------------------------------------------------------------
// W3t repack: chunk-major, pitch 128, 0.1 folded, PRE-SWIZZLED for LDS staging.
// Layout: chunk*8192 + swz*8 + (k&7) bf16, swz = (r*16 + (k>>3)) ^ (r&7).
// ---------------------------------------------------------------------------
__global__ __launch_bounds__(256) void prep_w3t_kernel(const float* __restrict__ W3,
                                                       __hip_bfloat16* __restrict__ W3t){
  int idx = blockIdx.x*256 + threadIdx.x;
  if (idx >= 1216*128) return;
  int cp = idx >> 7, k = idx & 127;
  int chunk = cp >> 6, r = cp & 63;
  int lo = CB_LO[chunk], li = CB_LI[chunk], lf = CB_LF[chunk];
  int lmin = lo<li ? lo : li;
  int nlf = 2*lmin+1;
  int fi = lf - (lo>li ? lo-li : li-lo);
  int c = ROFFT[lo][li] + r*nlf + fi;
  float v = (k < 100) ? 0.1f*W3[(size_t)k*NCOL + c] : 0.f;
  int swz = (r*16 + (k>>3)) ^ (r&7);
  W3t[(size_t)chunk*8192 + swz*8 + (k&7)] = __float2bfloat16(v);
}

// Wt[o][k] = bf16(0.1*W[k][o]), o<112 (rows 100..111 zero), k<136 (k>=100 zero)
// Both W1 and W2 in one launch.
__global__ __launch_bounds__(256) void prep_wt_kernel(const float* __restrict__ W1,
                                                      const float* __restrict__ W2,
                                                      __hip_bfloat16* __restrict__ W1t,
                                                      __hip_bfloat16* __restrict__ W2t){
  int idx = blockIdx.x*256 + threadIdx.x;
  constexpr int HALF = 112*136;
  if (idx >= 2*HALF) return;
  const float* W = (idx < HALF) ? W1 : W2;
  __hip_bfloat16* Wt = (idx < HALF) ? W1t : W2t;
  int r = (idx < HALF) ? idx : idx - HALF;
  int o = r/136, k = r%136;
  float v = (o < 100 && k < 100) ? 0.1f*W[k*100+o] : 0.f;
  Wt[r] = __float2bfloat16(v);
}

// ---------------------------------------------------------------------------
// Radial MLP with MFMA layers 2,3. 64 edges/block, 4 waves, 4 blocks/CU.
// ---------------------------------------------------------------------------
__device__ __forceinline__ float swishf(float s){
  return SWISH_SCALE * s / (1.f + __expf(-s));
}

__device__ __forceinline__ void radial_layer_mfma(
    const __hip_bfloat16* __restrict__ sIn,   // [64][136] bf16, rows e
    const __hip_bfloat16* __restrict__ Wt,    // [112][136] bf16 global
    __hip_bfloat16* __restrict__ sOut,        // [64][136] bf16
    int wv, int lr, int lq)
{
  bf16x8 bf[4];
  #pragma unroll
  for (int ks=0; ks<4; ++ks)
    bf[ks] = *(const bf16x8*)&sIn[(wv*16+lr)*136 + ks*32 + lq*8];
  f32x4 acc[7] = {};
  #pragma unroll
  for (int ks=0; ks<4; ++ks)
    #pragma unroll
    for (int ot=0; ot<7; ++ot){
      bf16x8 a = *(const bf16x8*)&Wt[(ot*16+lr)*136 + ks*32 + lq*8];
      acc[ot] = __builtin_amdgcn_mfma_f32_16x16x32_bf16(a, bf[ks], acc[ot], 0, 0, 0);
    }
  // C frag: col(lr)=e within wave, row(ot*16+lq*4+r)=o.  swish + bf16 + short4.
  #pragma unroll
  for (int ot=0; ot<7; ++ot){
    __hip_bfloat16 hv[4];
    #pragma unroll
    for (int r=0; r<4; ++r)
      hv[r] = __float2bfloat16(swishf(acc[ot][r]));   // Wt rows o>=100 zero -> swish(0)=0
    *(short4*)&sOut[(wv*16+lr)*136 + ot*16 + lq*4] = *(short4*)hv;
  }
  // zero o/k = 112..127 of own rows COMPLETELY: 64 lanes = 16 rows x 4 quarters
  {
    int lane = lq*16 + lr;            // 0..63
    int row = lane & 15, q = lane >> 4;   // q in 0..3
    short4 z = {0,0,0,0};
    *(short4*)&sOut[(wv*16+row)*136 + 112 + q*4] = z;
  }
}

__global__ __launch_bounds__(256,4) void radial_mfma_kernel(
    const float* __restrict__ radii, const float* __restrict__ W0,
    const __hip_bfloat16* __restrict__ W1t, const __hip_bfloat16* __restrict__ W2t,
    __hip_bfloat16* __restrict__ h_bf, int E)
{
  __shared__ float sbas[640];
  __shared__ __align__(16) __hip_bfloat16 sA[64*136];  // h1, then h3
  __shared__ __align__(16) __hip_bfloat16 sB[64*136];  // h2
  const int t = threadIdx.x;
  const int et0 = blockIdx.x*64;

  for (int p=t; p<640; p+=256){
    int er = p/10, k = p%10;
    int eg = et0 + er;
    float r = (eg < E) ? radii[eg] : 0.f;
    float c = 0.7f + (2.5f/9.0f)*(float)k;
    float d = (r - c) * (9.0f/2.5f);
    sbas[p] = __expf(-d*d);
  }
  __syncthreads();
  // layer 1 (K=10, VALU), h1 bf16 into sA; zero k-pad 100..135
  for (int p=t; p<6400; p+=256){
    int er = p/100, o = p%100;
    float s = 0.f;
    #pragma unroll
    for (int k=0;k<10;++k) s += sbas[er*10+k]*W0[k*100+o];
    sA[er*136+o] = __float2bfloat16(swishf(s*0.3162277660168379f));   // 1/sqrt(10)
  }
  for (int p=t; p<64*36; p+=256){
    int er = p/36, k = 100 + p%36;
    sA[er*136+k] = __float2bfloat16(0.f);
  }
  __syncthreads();   // everything below is wave-local (own 16 edge rows)

  const int lane = t & 63, wv = t >> 6;
  const int lr = lane & 15, lq = lane >> 4;

  radial_layer_mfma(sA, W1t, sB, wv, lr, lq);   // h2 = swish(0.1*h1@W1)
  __builtin_amdgcn_wave_barrier();
  radial_layer_mfma(sB, W2t, sA, wv, lr, lq);   // h3 = swish(0.1*h2@W2)
  __builtin_amdgcn_wave_barrier();
  // copy own 16 rows (16*136 bf16 = 272 float4) to global
  {
    const float4* sm = (const float4*)(sA + (size_t)(wv*16)*136);
    float4* gm = (float4*)(h_bf + (size_t)(et0 + wv*16)*136);
    for (int p=lane; p<272; p+=64) gm[p] = sm[p];
  }
}

// ---------------------------------------------------------------------------
// CSR of edges by target node
// ---------------------------------------------------------------------------
__global__ __launch_bounds__(256) void hist_kernel(const int* __restrict__ ei,
                                                   int* __restrict__ deg, int E){
  int e = blockIdx.x*256 + threadIdx.x;
  if (e < E) atomicAdd(&deg[ei[E+e]], 1);
}

__global__ __launch_bounds__(256) void scan_kernel(const int* __restrict__ deg,
                                                   int* __restrict__ off,
                                                   int* __restrict__ cursor, int N, int E){
  __shared__ int part[256], spref[256];
  const int t = threadIdx.x;
  const int CH = (N + 255)/256;
  int lo = t*CH, hi = lo+CH < N ? lo+CH : N;
  int s = 0;
  for (int n=lo; n<hi; ++n) s += deg[n];
  part[t] = s;
  __syncthreads();
  if (t == 0){
    int run = 0;
    for (int i=0;i<256;++i){ spref[i] = run; run += part[i]; }
  }
  __syncthreads();
  int run = spref[t];
  for (int n=lo; n<hi; ++n){ off[n] = run; cursor[n] = run; run += deg[n]; }
  if (t == 255) off[N] = E;
}

__global__ __launch_bounds__(256) void fill_kernel(const int* __restrict__ ei,
                                                   int* __restrict__ cursor,
                                                   int* __restrict__ eid, int E){
  int e = blockIdx.x*256 + threadIdx.x;
  if (e < E){
    int idx = atomicAdd(&cursor[ei[E+e]], 1);
    eid[idx] = e;
  }
}

// ---------------------------------------------------------------------------
// Gather: one 64-lane wave per node; writes every output element exactly once.
// ---------------------------------------------------------------------------
__global__ __launch_bounds__(64) void gather_kernel(const float* __restrict__ msg,
                                                    const int* __restrict__ off,
                                                    const int* __restrict__ eid,
                                                    float* __restrict__ out, int N){
  const int n = blockIdx.x;
  const int t = threadIdx.x;
  const int s = off[n], e1 = off[n+1];
  float a0 = 0.f, a1 = 0.f;
  for (int i=s; i<e1; ++i){
    const float* m = msg + (size_t)eid[i]*FEATD;
    a0 += m[t];
    if (t < 8) a1 += m[64+t];
  }
  out[(size_t)n*FEATD + t] = a0;
  if (t < 8) out[(size_t)n*FEATD + 64 + t] = a1;
}

// ---------------------------------------------------------------------------
// Fused GEMM+TP with LDS-staged W3t chunks. LDS 80432 B -> 2 blocks/CU.
// ---------------------------------------------------------------------------
constexpr int OF_W   = 0;         // 16384: staged W3t chunk (swizzled)
constexpr int OF_RT  = 16384;     // 64*68 f32 = 17408
constexpr int OF_ACC = 33792;     // 64*40 f32 = 10240 (live LO-group slice)
constexpr int OF_F   = 44032;     // 64*72 f32 = 18432
constexpr int OF_KV  = 62464;     // 64*25 f32 = 6400
constexpr int OF_RSH = 68864;     // 64*25 f32 = 6400
constexpr int OF_C3  = 75264;     // 1225 f32 = 4900
constexpr int OF_SRC = 80176;     // 64 int = 256
constexpr int SMEM_SZ = 80432;    // <= 81920 -> 2 blocks/CU

// stage one 16KB pre-swizzled chunk: 4 x global_load_lds(16B) per wave
__device__ __forceinline__ void stage_chunk(const __hip_bfloat16* __restrict__ W3t,
                                            int chunk, char* sW, int t)
{
  const int lane = t & 63, wv = t >> 6;
  const char* g = (const char*)W3t + (size_t)chunk*16384;
  #pragma unroll
  for (int r=0; r<4; ++r){
    const char* gsrc = g + (wv*256 + r*64 + lane)*16;
    __builtin_amdgcn_global_load_lds(
        (const __attribute__((address_space(1))) unsigned int*)gsrc,
        (__attribute__((address_space(3))) unsigned int*)(sW + wv*4096 + r*1024),
        16, 0, 0);
  }
}

template<int LO,int LI,int LF>
__device__ __forceinline__ void phase(
    int chunk, const __hip_bfloat16* __restrict__ W3t, const bf16x8 (&hf)[4],
    char* sW, float* sRt, float* sFf, float* sRsh, float* sKV, const float* sC3,
    float* sAcc, int t)
{
  constexpr int NO = 2*LO+1, NI = 2*LI+1, NF = 2*LF+1;
  constexpr int C3B = C3OFFT[LO][LI][LF];
  constexpr int FO  = FOFFT[LI];

  const int e = t >> 2, role = t & 3;
  const int lane = t & 63, wv = t >> 6;
  const int lr = lane & 15, lq = lane >> 4;

  __syncthreads();                       // all waves done reading prev sW
  stage_chunk(W3t, chunk, sW, t);        // issue coalesced stage (vmcnt)

  // ---- 1. kv[e][o*NI+mi] = sum_mf C3 * y  (overlaps stage latency) ----
  {
    float y[NF];
    #pragma unroll
    for (int mf=0; mf<NF; ++mf) y[mf] = sRsh[e*25 + LF*LF + mf];
    for (int it = role; it < NO*NI; it += 4){
      float s = 0.f;
      #pragma unroll
      for (int mf=0; mf<NF; ++mf) s += sC3[C3B + it*NF + mf] * y[mf];
      sKV[e*25 + it] = s;
    }
  }
  __syncthreads();                       // drains vmcnt(0): sW ready for all

  // ---- 2. MFMA: A fragments from LDS (swizzled ds_read_b128) ----
  {
    f32x4 a4[4] = {};
    #pragma unroll
    for (int ks=0; ks<4; ++ks){
      #pragma unroll
      for (int ct=0; ct<4; ++ct){
        const int row = ct*16 + lr;
        const int u   = (row*16 + (ks*4 + lq)) ^ (row & 7);
        bf16x8 a = *(const bf16x8*)(sW + u*16);
        a4[ct] = __builtin_amdgcn_mfma_f32_16x16x32_bf16(a, hf[ks], a4[ct], 0, 0, 0);
      }
    }
    #pragma unroll
    for (int ct=0; ct<4; ++ct)
      *(f32x4*)&sRt[(wv*16 + lr)*68 + ct*16 + lq*4] = a4[ct];
  }
  __builtin_amdgcn_wave_barrier();

  // ---- 3. consume (H-trick): H[du][mi] = sum_v R[u,v]*F[v,mi] ----
  {
    float H[2][NI];
    #pragma unroll
    for (int du=0; du<2; ++du)
      #pragma unroll
      for (int mi=0; mi<NI; ++mi) H[du][mi] = 0.f;

    #pragma unroll
    for (int vg=0; vg<2; ++vg){
      float fb[4*NI];
      #pragma unroll
      for (int p=0; p<NI; ++p)
        *(f32x4*)&fb[p*4] = *(const f32x4*)&sFf[e*72 + FO + vg*4*NI + p*4];
      #pragma unroll
      for (int du=0; du<2; ++du){
        const int u = role*2 + du;
        f32x4 rv = *(const f32x4*)&sRt[e*68 + u*8 + vg*4];
        #pragma unroll
        for (int v=0; v<4; ++v)
          #pragma unroll
          for (int mi=0; mi<NI; ++mi)
            H[du][mi] += rv[v] * fb[v*NI + mi];
      }
    }
    // accumulate into group-local LDS slice (pitch 40):
    // LO=0: col=u (0..7); LO=1: col=u*3+o (0..23); LO=2: col=u*5+o (0..39)
    const int u0 = role*2, u1 = role*2 + 1;
    const int b0 = e*40 + ((LO==0) ? u0 : (LO==1) ? u0*3 : u0*5);
    const int b1 = e*40 + ((LO==0) ? u1 : (LO==1) ? u1*3 : u1*5);
    #pragma unroll
    for (int o=0; o<NO; ++o){
      float s0 = 0.f, s1 = 0.f;
      #pragma unroll
      for (int mi=0; mi<NI; ++mi){
        float kvv = sKV[e*25 + o*NI + mi];
        s0 += kvv * H[0][mi];
        s1 += kvv * H[1][mi];
      }
      sAcc[b0 + o] += s0;
      sAcc[b1 + o] += s1;
    }
  }
  __builtin_amdgcn_wave_barrier();
}

// Wave-local flush of the LO-group accumulator slice.
template<int J0,int W>
__device__ __forceinline__ void flush_group(float* sAcc, float* __restrict__ msg,
                                            int eb, int t, float nrm)
{
  const int lane = t & 63, wv = t >> 6;
  __builtin_amdgcn_wave_barrier();
  for (int p = lane; p < 16*W; p += 64){
    int el = wv*16 + p/W, j = p%W;
    msg[(size_t)(eb + el)*FEATD + J0 + j] = nrm * sAcc[el*40 + j];
    sAcc[el*40 + j] = 0.f;                 // ready for next group
  }
  __builtin_amdgcn_wave_barrier();
}

__global__ __launch_bounds__(256,2) void fused_kernel(
    const float* __restrict__ feats, const int* __restrict__ ei,
    const float* __restrict__ rsh, const __hip_bfloat16* __restrict__ h_bf,
    const __hip_bfloat16* __restrict__ W3t, const float* __restrict__ C3g,
    float* __restrict__ msg, int E)
{
  __shared__ __align__(16) char smem[SMEM_SZ];
  char*  sW   = smem + OF_W;
  float* sRt  = (float*)(smem + OF_RT);
  float* sAcc = (float*)(smem + OF_ACC);
  float* sFf  = (float*)(smem + OF_F);
  float* sKV  = (float*)(smem + OF_KV);
  float* sRsh = (float*)(smem + OF_RSH);
  float* sC3  = (float*)(smem + OF_C3);
  int*   sSrc = (int*)(smem + OF_SRC);

  const int t = threadIdx.x;
  const int eb = blockIdx.x*64;

  bf16x8 hf[4];
  {
    const int lane = t & 63, wv = t >> 6;
    const int lr = lane & 15, lq = lane >> 4;
    const __hip_bfloat16* hrow = h_bf + (size_t)(eb + wv*16 + lr)*136;
    #pragma unroll
    for (int ks=0; ks<4; ++ks)
      hf[ks] = *(const bf16x8*)&hrow[ks*32 + lq*8];
  }
  for (int p=t; p<2560; p+=256) sAcc[p] = 0.f;
  for (int p=t; p<64; p+=256){
    int e = eb + p;
    sSrc[p] = (e < E) ? ei[e] : 0;
  }
  for (int p=t; p<1600; p+=256){
    int el = p/25, j = p%25;
    int e = eb + el;
    sRsh[el*25 + j] = (e < E) ? rsh[(size_t)e*25 + j] : 0.f;
  }
  for (int p=t; p<C3TOT; p+=256) sC3[p] = C3g[p];
  __syncthreads();
  for (int p=t; p<64*72; p+=256){
    int el = p/72, j = p%72;
    sFf[el*72 + j] = feats[(size_t)sSrc[el]*72 + j];
  }
  __syncthreads();

  // ---- group LO=0: output cols 0..7 ----
  phase<0,0,0>( 0, W3t, hf, sW, sRt, sFf, sRsh, sKV, sC3, sAcc, t);
  phase<0,1,1>( 1, W3t, hf, sW, sRt, sFf, sRsh, sKV, sC3, sAcc, t);
  phase<0,2,2>( 2, W3t, hf, sW, sRt, sFf, sRsh, sKV, sC3, sAcc, t);
  flush_group<0,8>(sAcc, msg, eb, t, 0.72360125f);

  // ---- group LO=1: output cols 8..31 ----
  phase<1,0,1>( 3, W3t, hf, sW, sRt, sFf, sRsh, sKV, sC3, sAcc, t);
  phase<1,1,0>( 4, W3t, hf, sW, sRt, sFf, sRsh, sKV, sC3, sAcc, t);
  phase<1,1,1>( 5, W3t, hf, sW, sRt, sFf, sRsh, sKV, sC3, sAcc, t);
  phase<1,1,2>( 6, W3t, hf, sW, sRt, sFf, sRsh, sKV, sC3, sAcc, t);
  phase<1,2,1>( 7, W3t, hf, sW, sRt, sFf, sRsh, sKV, sC3, sAcc, t);
  phase<1,2,2>( 8, W3t, hf, sW, sRt, sFf, sRsh, sKV, sC3, sAcc, t);
  phase<1,2,3>( 9, W3t, hf, sW, sRt, sFf, sRsh, sKV, sC3, sAcc, t);
  flush_group<8,24>(sAcc, msg, eb, t, 0.8204867f);

  // ---- group LO=2: output cols 32..71 ----
  phase<2,0,2>(10, W3t, hf, sW, sRt, sFf, sRsh, sKV, sC3, sAcc, t);
  phase<2,1,1>(11, W3t, hf, sW, sRt, sFf, sRsh, sKV, sC3, sAcc, t);
  phase<2,1,2>(12, W3t, hf, sW, sRt, sFf, sRsh, sKV, sC3, sAcc, t);
  phase<2,1,3>(13, W3t, hf, sW, sRt, sFf, sRsh, sKV, sC3, sAcc, t);
  phase<2,2,0>(14, W3t, hf, sW, sRt, sFf, sRsh, sKV, sC3, sAcc, t);
  phase<2,2,1>(15, W3t, hf, sW, sRt, sFf, sRsh, sKV, sC3, sAcc, t);
  phase<2,2,2>(16, W3t, hf, sW, sRt, sFf, sRsh, sKV, sC3, sAcc, t);
  phase<2,2,3>(17, W3t, hf, sW, sRt, sFf, sRsh, sKV, sC3, sAcc, t);
  phase<2,2,4>(18, W3t, hf, sW, sRt, sFf, sRsh, sKV, sC3, sAcc, t);
  flush_group<32,40>(sAcc, msg, eb, t, 0.9341652f);
}

// ---------------------------------------------------------------------------
extern "C" void kernel_launch(void* const* d_in, const int* in_sizes, int n_in,
                              void* d_out, int out_size, void* d_ws, size_t ws_size,
                              hipStream_t stream)
{
  const float* feats = (const float*)d_in[0];
  const int*   ei    = (const int*)d_in[1];
  const float* radii = (const float*)d_in[2];
  const float* rsh   = (const float*)d_in[3];
  const float* W0    = (const float*)d_in[4];
  const float* W1    = (const float*)d_in[5];
  const float* W2    = (const float*)d_in[6];
  const float* W3    = (const float*)d_in[7];
  float* out = (float*)d_out;
  const int E = in_sizes[2];
  const int N = in_sizes[0]/FEATD;

  const int EPAD = ((E + 63)/64)*64;
  const int NBLK = EPAD/64;

  char* ws = (char*)d_ws;
  size_t off_b = 0;
  float*  C3f = (float*)(ws + off_b);  off_b += 8192;
  double* Tre = (double*)(ws + off_b); off_b += 12288;
  double* Tim = (double*)(ws + off_b); off_b += 12288;          // 32768
  __hip_bfloat16* W3t = (__hip_bfloat16*)(ws + off_b); off_b += 335872;  // 19*16KB used
  __hip_bfloat16* W1t = (__hip_bfloat16*)(ws + off_b); off_b += 30720;   // 112*136 bf16
  __hip_bfloat16* W2t = (__hip_bfloat16*)(ws + off_b); off_b += 30720;
  __hip_bfloat16* h_bf = (__hip_bfloat16*)(ws + off_b); off_b += (size_t)EPAD*272;
  float* msg = (float*)(ws + off_b);   off_b += (size_t)EPAD*FEATD*4;
  int* deg    = (int*)(ws + off_b);    off_b += (size_t)N*4;
  int* offv   = (int*)(ws + off_b);    off_b += (size_t)(N+1)*4;
  int* cursor = (int*)(ws + off_b);    off_b += (size_t)N*4;
  int* eid    = (int*)(ws + off_b);    off_b += (size_t)E*4;

  // constants / tables
  c3_build_kernel<<<dim3((C3TOT+63)/64), dim3(64), 0, stream>>>(Tre, Tim);
  c3_norm_kernel<<<dim3(NCOMBO), dim3(64), 0, stream>>>(Tre, Tim, C3f);
  prep_w3t_kernel<<<dim3((1216*128+255)/256), dim3(256), 0, stream>>>(W3, W3t);
  prep_wt_kernel<<<dim3((2*112*136+255)/256), dim3(256), 0, stream>>>(W1, W2, W1t, W2t);

  // CSR of edges by target
  hipMemsetAsync(deg, 0, (size_t)N*4, stream);
  hist_kernel<<<dim3((E+255)/256), dim3(256), 0, stream>>>(ei, deg, E);
  scan_kernel<<<dim3(1), dim3(256), 0, stream>>>(deg, offv, cursor, N, E);
  fill_kernel<<<dim3((E+255)/256), dim3(256), 0, stream>>>(ei, cursor, eid, E);

  // main pipeline
  radial_mfma_kernel<<<dim3(NBLK), dim3(256), 0, stream>>>(radii, W0, W1t, W2t, h_bf, E);
  fused_kernel<<<dim3(NBLK), dim3(256), 0, stream>>>(feats, ei, rsh, h_bf, W3t, C3f, msg, E);
  gather_kernel<<<dim3(N), dim3(64), 0, stream>>>(msg, offv, eid, out, N);
}